// Round 16
// baseline (199.027 us; speedup 1.0000x reference)
//
#include <hip/hip_runtime.h>
#include <math.h>

#define NEG_SLOPE 0.2f

typedef float f32x4 __attribute__((ext_vector_type(4)));
typedef short bf16x8 __attribute__((ext_vector_type(8)));
typedef unsigned short ushortv8 __attribute__((ext_vector_type(8)));

__device__ __forceinline__ unsigned short f2bf(float f) {
    union { float f; unsigned u; } uu; uu.f = f;
    unsigned r = uu.u + 0x7FFF + ((uu.u >> 16) & 1);   // RNE, no NaN inputs
    return (unsigned short)(r >> 16);
}
__device__ __forceinline__ float bf2f(unsigned short u) {
    union { unsigned u; float f; } x; x.u = ((unsigned)u) << 16; return x.f;
}

// ---------------------------------------------------------------------------
// prep: W1 transpose | W2 transpose | zero counts+cursor.
// ---------------------------------------------------------------------------
__global__ void prep_kernel(const float* __restrict__ W1, unsigned short* __restrict__ Wt1,
                            const float* __restrict__ W2, unsigned short* __restrict__ Wt2,
                            int* __restrict__ counts, int* __restrict__ cursor, int N)
{
    int u = blockIdx.x * 256 + threadIdx.x;
    if (u < 32768) {                       // Wt1[256][128]
        int nn = u >> 7, k = u & 127;
        Wt1[u] = f2bf(W1[(size_t)k * 256 + nn]);
        return;
    }
    u -= 32768;
    if (u < 65536) {                       // Wt2[256][256]
        int nn = u >> 8, k = u & 255;
        Wt2[u] = f2bf(W2[(size_t)k * 256 + nn]);
        return;
    }
    u -= 65536;
    if (u < N) { counts[u] = 0; cursor[u] = 0; }
}

__global__ void hist_kernel(const int* __restrict__ dst, int* __restrict__ counts, int E)
{
    int e = blockIdx.x * 256 + threadIdx.x;
    if (e < E) atomicAdd(&counts[dst[e]], 1);
}

// ---------------------------------------------------------------------------
// Barrier-free direct-from-global MFMA GEMM. 256 thr = 4 waves; wave wc owns
// rows [blockIdx.x*64, +64) x cols [wc*64, +64) with acc[4][4]. Fragments are
// loaded straight from global (A: 16B/lane contiguous in K; B: Wt L2-resident)
// — no LDS, no __syncthreads, K-loop fully unrolled (K is template const) so
// the compiler pipelines loads across K-steps. Fused att epilogue; CSR-fill
// piggyback blocks appended after gemmBlocks.
// ---------------------------------------------------------------------------
template<int CVT, int KC>
__global__ __launch_bounds__(256) void gemm_mfma(
    const void* __restrict__ Av,               // [M][KC] f32 (CVT) or bf16
    const unsigned short* __restrict__ Bt,     // [256][KC] bf16
    unsigned short* __restrict__ C,            // [M][256] bf16
    const float* __restrict__ att_s,           // flat [256]
    const float* __restrict__ att_d,
    float* __restrict__ a_s,                   // [M][8]
    float* __restrict__ a_d,
    int M, int gemmBlocks,
    const int* __restrict__ srcp, const int* __restrict__ dstp,
    const int* __restrict__ incl, const int* __restrict__ bsum,
    int* __restrict__ rowptr, int* __restrict__ cursor,
    int* __restrict__ esrc, int E)
{
    if ((int)blockIdx.x >= gemmBlocks) {       // ---- CSR fill path ----
        int t = ((int)blockIdx.x - gemmBlocks) * 256 + threadIdx.x;
        if (t < M) {
            rowptr[t + 1] = incl[t] + bsum[t >> 8];
            if (t == 0) rowptr[0] = 0;
        }
        if (t < E) {
            int d = dstp[t];
            int rp = bsum[d >> 8] + ((d & 255) ? incl[d - 1] : 0);
            int pos = rp + atomicAdd(&cursor[d], 1);
            esrc[pos] = srcp[t];
        }
        return;
    }

    const int tid  = threadIdx.x;
    const int lane = tid & 63;
    const int wc   = tid >> 6;                 // wave = col strip
    const int row0 = blockIdx.x * 64;
    const int l15  = lane & 15;
    const int kg   = (lane >> 4) * 8;          // k sub-offset of this lane

    int rowm[4];
    #pragma unroll
    for (int m = 0; m < 4; ++m) {
        int r = row0 + m * 16 + l15;
        rowm[m] = (r < M) ? r : (M - 1);
    }
    int coln[4];
    #pragma unroll
    for (int n = 0; n < 4; ++n) coln[n] = wc * 64 + n * 16 + l15;

    f32x4 acc[4][4] = {};

    #pragma unroll
    for (int ks = 0; ks < KC / 32; ++ks) {
        const int k = ks * 32 + kg;
        bf16x8 af[4], bfr[4];
        #pragma unroll
        for (int m = 0; m < 4; ++m) {
            if constexpr (CVT) {
                const float* ap = (const float*)Av + (size_t)rowm[m] * KC + k;
                float4 lo = *(const float4*)ap;
                float4 hi = *(const float4*)(ap + 4);
                ushortv8 o;
                o[0]=f2bf(lo.x); o[1]=f2bf(lo.y); o[2]=f2bf(lo.z); o[3]=f2bf(lo.w);
                o[4]=f2bf(hi.x); o[5]=f2bf(hi.y); o[6]=f2bf(hi.z); o[7]=f2bf(hi.w);
                af[m] = (bf16x8)o;
            } else {
                af[m] = *(const bf16x8*)((const unsigned short*)Av +
                                         (size_t)rowm[m] * KC + k);
            }
        }
        #pragma unroll
        for (int n = 0; n < 4; ++n)
            bfr[n] = *(const bf16x8*)(Bt + (size_t)coln[n] * KC + k);
        #pragma unroll
        for (int m = 0; m < 4; ++m)
            #pragma unroll
            for (int n = 0; n < 4; ++n)
                acc[m][n] = __builtin_amdgcn_mfma_f32_16x16x32_bf16(
                    af[m], bfr[n], acc[m][n], 0, 0, 0);
    }

    // ---- C store ----
    #pragma unroll
    for (int m = 0; m < 4; ++m) {
        int rbase = row0 + m * 16 + ((lane >> 4) << 2);
        #pragma unroll
        for (int j = 0; j < 4; ++j) {
            int grow = rbase + j;
            if (grow < M) {
                #pragma unroll
                for (int n = 0; n < 4; ++n)
                    C[(size_t)grow * 256 + wc * 64 + n * 16 + l15] =
                        f2bf(acc[m][n][j]);
            }
        }
    }

    // ---- fused attention logits (wave covers heads wc*2, wc*2+1) ----
    float asv[4], adv[4];
    #pragma unroll
    for (int n = 0; n < 4; ++n) {
        int colg = wc * 64 + n * 16 + l15;
        asv[n] = att_s[colg];
        adv[n] = att_d[colg];
    }
    const int hbase = wc * 2;
    #pragma unroll
    for (int m = 0; m < 4; ++m) {
        int rbase = row0 + m * 16 + ((lane >> 4) << 2);
        #pragma unroll
        for (int j = 0; j < 4; ++j) {
            int grow = rbase + j;
            #pragma unroll
            for (int t = 0; t < 2; ++t) {
                float vs = acc[m][2*t][j] * asv[2*t] + acc[m][2*t+1][j] * asv[2*t+1];
                float vd = acc[m][2*t][j] * adv[2*t] + acc[m][2*t+1][j] * adv[2*t+1];
                #pragma unroll
                for (int off = 1; off < 16; off <<= 1) {
                    vs += __shfl_xor(vs, off);
                    vd += __shfl_xor(vd, off);
                }
                if (l15 == 0 && grow < M) {
                    a_s[(size_t)grow * 8 + hbase + t] = vs;
                    a_d[(size_t)grow * 8 + hbase + t] = vd;
                }
            }
        }
    }
}

// ---------------------------------------------------------------------------
// CSR scan kernels (verbatim)
// ---------------------------------------------------------------------------
__global__ __launch_bounds__(256) void scan_blk(
    const int* __restrict__ counts, int* __restrict__ incl, int* __restrict__ bsum, int N)
{
    __shared__ int wtot[4], wexc[4];
    int t = blockIdx.x * 256 + threadIdx.x;
    int lane = threadIdx.x & 63, wid = threadIdx.x >> 6;
    int v = (t < N) ? counts[t] : 0;
    int s = v;
    #pragma unroll
    for (int off = 1; off < 64; off <<= 1) {
        int u = __shfl_up(s, off);
        if (lane >= off) s += u;
    }
    if (lane == 63) wtot[wid] = s;
    __syncthreads();
    if (threadIdx.x == 0) {
        int r = 0;
        #pragma unroll
        for (int w = 0; w < 4; ++w) { wexc[w] = r; r += wtot[w]; }
    }
    __syncthreads();
    int out = s + wexc[wid];
    if (t < N) incl[t] = out;
    if (threadIdx.x == 255) bsum[blockIdx.x] = out;
}

__global__ __launch_bounds__(256) void scan_top(int* __restrict__ bsum, int nb)
{
    __shared__ int wtot[4], wexc[4];
    int tid = threadIdx.x;
    int lane = tid & 63, wid = tid >> 6;
    int v = (tid < nb) ? bsum[tid] : 0;
    int s = v;
    #pragma unroll
    for (int off = 1; off < 64; off <<= 1) {
        int u = __shfl_up(s, off);
        if (lane >= off) s += u;
    }
    if (lane == 63) wtot[wid] = s;
    __syncthreads();
    if (tid == 0) {
        int r = 0;
        #pragma unroll
        for (int w = 0; w < 4; ++w) { wexc[w] = r; r += wtot[w]; }
    }
    __syncthreads();
    if (tid < nb) bsum[tid] = s + wexc[wid] - v;
}

// ---------------------------------------------------------------------------
// Per-node GAT aggregation — node-per-half geometry (verbatim best).
// ---------------------------------------------------------------------------
template<int LAYER>
__global__ __launch_bounds__(128) void gat_agg(
    const unsigned short* __restrict__ h, const float* __restrict__ a_s,
    const float* __restrict__ a_d, const int* __restrict__ rowptr,
    const int* __restrict__ esrc, const float* __restrict__ bias,
    float* __restrict__ out, unsigned short* __restrict__ out_b, int N)
{
    const int n  = blockIdx.x * 4 + (threadIdx.x >> 5);
    if (n >= N) return;
    const int sl   = threadIdx.x & 31;
    const int head = sl >> 2;
    const int beg = rowptr[n];
    const int deg = rowptr[n + 1] - beg;

    const float adn = a_d[(size_t)n*8 + head];
    float dsum = 0.f;
    float2 acc2[4] = {{0.f,0.f},{0.f,0.f},{0.f,0.f},{0.f,0.f}};

    int j0 = 0;
    for (; j0 + 4 <= deg; j0 += 4) {
        int s0 = esrc[beg + j0 + 0];
        int s1 = esrc[beg + j0 + 1];
        int s2 = esrc[beg + j0 + 2];
        int s3 = esrc[beg + j0 + 3];
        int sv[4] = {s0, s1, s2, s3};
        #pragma unroll
        for (int k = 0; k < 4; ++k) {
            int s = sv[k];
            float e = a_s[(size_t)s*8 + head] + adn;
            e = fmaxf(e, NEG_SLOPE * e);
            float p = __expf(e);
            dsum += p;
            uint4 hv = *(const uint4*)(h + (size_t)s*256 + sl*8);
            const unsigned* hw = (const unsigned*)&hv;
            #pragma unroll
            for (int i = 0; i < 4; ++i) {
                acc2[i].x += p * __uint_as_float(hw[i] << 16);
                acc2[i].y += p * __uint_as_float(hw[i] & 0xffff0000u);
            }
        }
    }
    for (; j0 < deg; ++j0) {
        int s = esrc[beg + j0];
        float e = a_s[(size_t)s*8 + head] + adn;
        e = fmaxf(e, NEG_SLOPE * e);
        float p = __expf(e);
        dsum += p;
        uint4 hv = *(const uint4*)(h + (size_t)s*256 + sl*8);
        const unsigned* hw = (const unsigned*)&hv;
        #pragma unroll
        for (int i = 0; i < 4; ++i) {
            acc2[i].x += p * __uint_as_float(hw[i] << 16);
            acc2[i].y += p * __uint_as_float(hw[i] & 0xffff0000u);
        }
    }

    float invd = 1.f / (dsum + 1e-16f);

    if (LAYER == 1) {
        ushortv8 o;
        #pragma unroll
        for (int i = 0; i < 4; ++i) {
            float v0 = acc2[i].x * invd + bias[sl*8 + 2*i];
            float v1 = acc2[i].y * invd + bias[sl*8 + 2*i + 1];
            o[2*i]   = f2bf(v0 > 0.f ? v0 : expf(v0) - 1.f);
            o[2*i+1] = f2bf(v1 > 0.f ? v1 : expf(v1) - 1.f);
        }
        *(ushortv8*)(out_b + (size_t)n*256 + sl*8) = o;
    } else {
        #pragma unroll
        for (int i = 0; i < 4; ++i) { acc2[i].x *= invd; acc2[i].y *= invd; }
        #pragma unroll
        for (int m = 4; m <= 16; m <<= 1)
            #pragma unroll
            for (int i = 0; i < 4; ++i) {
                acc2[i].x += __shfl_xor(acc2[i].x, m);
                acc2[i].y += __shfl_xor(acc2[i].y, m);
            }
        if (sl < 4) {
            float4 lo = make_float4(acc2[0].x*0.125f + bias[sl*8+0],
                                    acc2[0].y*0.125f + bias[sl*8+1],
                                    acc2[1].x*0.125f + bias[sl*8+2],
                                    acc2[1].y*0.125f + bias[sl*8+3]);
            float4 hi = make_float4(acc2[2].x*0.125f + bias[sl*8+4],
                                    acc2[2].y*0.125f + bias[sl*8+5],
                                    acc2[3].x*0.125f + bias[sl*8+6],
                                    acc2[3].y*0.125f + bias[sl*8+7]);
            *(float4*)(out + (size_t)n*32 + sl*8)     = lo;
            *(float4*)(out + (size_t)n*32 + sl*8 + 4) = hi;
        }
    }
}

// ---------------------------------------------------------------------------
extern "C" void kernel_launch(void* const* d_in, const int* in_sizes, int n_in,
                              void* d_out, int out_size, void* d_ws, size_t ws_size,
                              hipStream_t stream)
{
    const float* x   = (const float*)d_in[0];
    const int*   ei  = (const int*)  d_in[1];
    const float* W1  = (const float*)d_in[2];
    const float* as1 = (const float*)d_in[3];
    const float* ad1 = (const float*)d_in[4];
    const float* b1  = (const float*)d_in[5];
    const float* W2  = (const float*)d_in[6];
    const float* as2 = (const float*)d_in[7];
    const float* ad2 = (const float*)d_in[8];
    const float* b2  = (const float*)d_in[9];

    const int N = in_sizes[0] / 128;
    const int E = in_sizes[1] / 2;
    const int* srcp = ei;
    const int* dstp = ei + E;

    // ---- workspace layout ----
    char* ws = (char*)d_ws;
    unsigned short* hb    = (unsigned short*)ws;  ws += (size_t)N * 256 * 2;
    unsigned short* out1b = (unsigned short*)ws;  ws += (size_t)N * 256 * 2;
    unsigned short* Wt1   = (unsigned short*)ws;  ws += 256 * 128 * 2;
    unsigned short* Wt2   = (unsigned short*)ws;  ws += 256 * 256 * 2;
    float*          a_s   = (float*)ws;           ws += (size_t)N * 8 * 4;
    float*          a_d   = (float*)ws;           ws += (size_t)N * 8 * 4;
    int*            counts= (int*)ws;             ws += (size_t)N * 4;
    int*            cursor= (int*)ws;             ws += (size_t)N * 4;
    int*            incl  = (int*)ws;             ws += (size_t)N * 4;
    int*            bsum  = (int*)ws;             ws += 256 * 4;
    int*            rowptr= (int*)ws;             ws += (size_t)(N + 1) * 4;
    int*            esrc  = (int*)ws;

    const int nb = (N + 255) / 256;

    {
        int tot = 32768 + 65536 + N;
        prep_kernel<<<(tot + 255) / 256, 256, 0, stream>>>(
            W1, Wt1, W2, Wt2, counts, cursor, N);
    }
    hist_kernel<<<(E + 255) / 256, 256, 0, stream>>>(dstp, counts, E);
    scan_blk<<<nb, 256, 0, stream>>>(counts, incl, bsum, N);
    scan_top<<<1, 256, 0, stream>>>(bsum, nb);

    const int gridM = (N + 63) / 64;
    const int fillB = (E + 255) / 256;

    // ---- layer 1: gemm1 (+ piggy-backed CSR fill blocks) ----
    gemm_mfma<1, 128><<<gridM + fillB, 256, 0, stream>>>(
        x, Wt1, hb, as1, ad1, a_s, a_d, N, gridM,
        srcp, dstp, incl, bsum, rowptr, cursor, esrc, E);
    gat_agg<1><<<(N + 3) / 4, 128, 0, stream>>>(hb, a_s, a_d, rowptr, esrc, b1,
                                                nullptr, out1b, N);

    // ---- layer 2 ----
    gemm_mfma<0, 256><<<gridM, 256, 0, stream>>>(
        out1b, Wt2, hb, as2, ad2, a_s, a_d, N, gridM,
        srcp, dstp, incl, bsum, rowptr, cursor, esrc, E);
    gat_agg<2><<<(N + 3) / 4, 128, 0, stream>>>(hb, a_s, a_d, rowptr, esrc, b2,
                                                (float*)d_out, nullptr, N);
}

// Round 17
// 174.361 us; speedup vs baseline: 1.1415x; 1.1415x over previous
//
#include <hip/hip_runtime.h>
#include <math.h>

#define NEG_SLOPE 0.2f

typedef float f32x4 __attribute__((ext_vector_type(4)));
typedef short bf16x8 __attribute__((ext_vector_type(8)));
typedef unsigned short ushortv8 __attribute__((ext_vector_type(8)));

__device__ __forceinline__ unsigned short f2bf(float f) {
    union { float f; unsigned u; } uu; uu.f = f;
    unsigned r = uu.u + 0x7FFF + ((uu.u >> 16) & 1);   // RNE, no NaN inputs
    return (unsigned short)(r >> 16);
}
__device__ __forceinline__ float bf2f(unsigned short u) {
    union { unsigned u; float f; } x; x.u = ((unsigned)u) << 16; return x.f;
}

// ---------------------------------------------------------------------------
// prep: W1 transpose | W2 transpose | zero counts+cursor.
// ---------------------------------------------------------------------------
__global__ void prep_kernel(const float* __restrict__ W1, unsigned short* __restrict__ Wt1,
                            const float* __restrict__ W2, unsigned short* __restrict__ Wt2,
                            int* __restrict__ counts, int* __restrict__ cursor, int N)
{
    int u = blockIdx.x * 256 + threadIdx.x;
    if (u < 32768) {                       // Wt1[256][128]
        int nn = u >> 7, k = u & 127;
        Wt1[u] = f2bf(W1[(size_t)k * 256 + nn]);
        return;
    }
    u -= 32768;
    if (u < 65536) {                       // Wt2[256][256]
        int nn = u >> 8, k = u & 255;
        Wt2[u] = f2bf(W2[(size_t)k * 256 + nn]);
        return;
    }
    u -= 65536;
    if (u < N) { counts[u] = 0; cursor[u] = 0; }
}

__global__ void hist_kernel(const int* __restrict__ dst, int* __restrict__ counts, int E)
{
    int e = blockIdx.x * 256 + threadIdx.x;
    if (e < E) atomicAdd(&counts[dst[e]], 1);
}

// ---------------------------------------------------------------------------
// MFMA GEMM — r15 best (LDS-staged BM=64 x BN=256, 512 thr, 8 waves 2x4,
// pipelined staging, fused att epilogue, piggy-backed CSR fill). Verbatim.
// ---------------------------------------------------------------------------
template<int CVT>
__global__ __launch_bounds__(512) void gemm_mfma(
    const void* __restrict__ Av,
    const unsigned short* __restrict__ Bt,     // [256][K]
    unsigned short* __restrict__ C,            // [M][256]
    const float* __restrict__ att_s,           // flat [256]
    const float* __restrict__ att_d,
    float* __restrict__ a_s,                   // [M][8]
    float* __restrict__ a_d,
    int M, int K, int gemmBlocks,
    const int* __restrict__ srcp, const int* __restrict__ dstp,
    const int* __restrict__ incl, const int* __restrict__ bsum,
    int* __restrict__ rowptr, int* __restrict__ cursor,
    int* __restrict__ esrc, int E)
{
    __shared__ unsigned short As[64 * 64];     // 8KB
    __shared__ unsigned short Bs[256 * 64];    // 32KB

    if ((int)blockIdx.x >= gemmBlocks) {       // ---- CSR fill path ----
        int t = ((int)blockIdx.x - gemmBlocks) * 512 + threadIdx.x;
        if (t < M) {
            rowptr[t + 1] = incl[t] + bsum[t >> 8];
            if (t == 0) rowptr[0] = 0;
        }
        if (t < E) {
            int d = dstp[t];
            int rp = bsum[d >> 8] + ((d & 255) ? incl[d - 1] : 0);
            int pos = rp + atomicAdd(&cursor[d], 1);
            esrc[pos] = srcp[t];
        }
        return;
    }

    const int tid  = threadIdx.x;
    const int lane = tid & 63;
    const int wave = tid >> 6;
    const int wr = wave >> 2, wc = wave & 3;   // 2x4 wave grid, 32x64 each
    const int row0 = blockIdx.x * 64;

    f32x4 acc[2][4] = {};
    ushortv8 va, vb[4];

    auto load_tile = [&](int k0) {
        {                                      // A: 512 chunks / 512 thr
            int r  = tid >> 3, cc = tid & 7;
            int ga = row0 + r; if (ga >= M) ga = M - 1;
            if constexpr (CVT) {
                const float* ap = (const float*)Av + (size_t)ga * K + k0 + cc * 8;
                float4 lo = *(const float4*)ap;
                float4 hi = *(const float4*)(ap + 4);
                ushortv8 o;
                o[0]=f2bf(lo.x); o[1]=f2bf(lo.y); o[2]=f2bf(lo.z); o[3]=f2bf(lo.w);
                o[4]=f2bf(hi.x); o[5]=f2bf(hi.y); o[6]=f2bf(hi.z); o[7]=f2bf(hi.w);
                va = o;
            } else {
                va = *(const ushortv8*)((const unsigned short*)Av +
                                        (size_t)ga * K + k0 + cc * 8);
            }
        }
        #pragma unroll
        for (int i = 0; i < 4; ++i) {          // B: 2048 chunks / 512 thr
            int c  = i * 512 + tid;
            int r  = c >> 3, cc = c & 7;
            vb[i] = *(const ushortv8*)(Bt + (size_t)r * K + k0 + cc * 8);
        }
    };

    load_tile(0);                              // prologue

    for (int k0 = 0; k0 < K; k0 += 64) {
        __syncthreads();                       // prior MFMA done reading LDS
        {
            int r  = tid >> 3, cc = tid & 7;
            *(ushortv8*)(As + r * 64 + (cc ^ (r & 7)) * 8) = va;
        }
        #pragma unroll
        for (int i = 0; i < 4; ++i) {
            int c  = i * 512 + tid;
            int r  = c >> 3, cc = c & 7;
            *(ushortv8*)(Bs + r * 64 + (cc ^ (r & 7)) * 8) = vb[i];
        }
        __syncthreads();

        if (k0 + 64 < K) load_tile(k0 + 64);   // latency hides under MFMAs

        #pragma unroll
        for (int kk = 0; kk < 2; ++kk) {
            const int kbyte = kk * 64 + ((lane >> 4) << 4);
            bf16x8 af[2], bfr[4];
            #pragma unroll
            for (int m = 0; m < 2; ++m) {
                int r = wr * 32 + m * 16 + (lane & 15);
                af[m] = *(const bf16x8*)((const char*)As + r * 128 + (kbyte ^ ((r & 7) << 4)));
            }
            #pragma unroll
            for (int n = 0; n < 4; ++n) {
                int r = wc * 64 + n * 16 + (lane & 15);
                bfr[n] = *(const bf16x8*)((const char*)Bs + r * 128 + (kbyte ^ ((r & 7) << 4)));
            }
            #pragma unroll
            for (int m = 0; m < 2; ++m)
                #pragma unroll
                for (int n = 0; n < 4; ++n)
                    acc[m][n] = __builtin_amdgcn_mfma_f32_16x16x32_bf16(
                        af[m], bfr[n], acc[m][n], 0, 0, 0);
        }
    }

    // ---- C store ----
    #pragma unroll
    for (int m = 0; m < 2; ++m) {
        int rbase = row0 + wr * 32 + m * 16 + ((lane >> 4) << 2);
        #pragma unroll
        for (int j = 0; j < 4; ++j) {
            int grow = rbase + j;
            if (grow < M) {
                #pragma unroll
                for (int n = 0; n < 4; ++n)
                    C[(size_t)grow * 256 + wc * 64 + n * 16 + (lane & 15)] =
                        f2bf(acc[m][n][j]);
            }
        }
    }

    // ---- fused attention logits (block covers all 8 heads; wave: 2wc,2wc+1)
    float asv[4], adv[4];
    #pragma unroll
    for (int n = 0; n < 4; ++n) {
        int colg = wc * 64 + n * 16 + (lane & 15);
        asv[n] = att_s[colg];
        adv[n] = att_d[colg];
    }
    const int hbase = wc * 2;
    #pragma unroll
    for (int m = 0; m < 2; ++m) {
        int rbase = row0 + wr * 32 + m * 16 + ((lane >> 4) << 2);
        #pragma unroll
        for (int j = 0; j < 4; ++j) {
            int grow = rbase + j;
            #pragma unroll
            for (int t = 0; t < 2; ++t) {
                float vs = acc[m][2*t][j] * asv[2*t] + acc[m][2*t+1][j] * asv[2*t+1];
                float vd = acc[m][2*t][j] * adv[2*t] + acc[m][2*t+1][j] * adv[2*t+1];
                #pragma unroll
                for (int off = 1; off < 16; off <<= 1) {
                    vs += __shfl_xor(vs, off);
                    vd += __shfl_xor(vd, off);
                }
                if ((lane & 15) == 0 && grow < M) {
                    a_s[(size_t)grow * 8 + hbase + t] = vs;
                    a_d[(size_t)grow * 8 + hbase + t] = vd;
                }
            }
        }
    }
}

// ---------------------------------------------------------------------------
// CSR scan kernels (verbatim)
// ---------------------------------------------------------------------------
__global__ __launch_bounds__(256) void scan_blk(
    const int* __restrict__ counts, int* __restrict__ incl, int* __restrict__ bsum, int N)
{
    __shared__ int wtot[4], wexc[4];
    int t = blockIdx.x * 256 + threadIdx.x;
    int lane = threadIdx.x & 63, wid = threadIdx.x >> 6;
    int v = (t < N) ? counts[t] : 0;
    int s = v;
    #pragma unroll
    for (int off = 1; off < 64; off <<= 1) {
        int u = __shfl_up(s, off);
        if (lane >= off) s += u;
    }
    if (lane == 63) wtot[wid] = s;
    __syncthreads();
    if (threadIdx.x == 0) {
        int r = 0;
        #pragma unroll
        for (int w = 0; w < 4; ++w) { wexc[w] = r; r += wtot[w]; }
    }
    __syncthreads();
    int out = s + wexc[wid];
    if (t < N) incl[t] = out;
    if (threadIdx.x == 255) bsum[blockIdx.x] = out;
}

__global__ __launch_bounds__(256) void scan_top(int* __restrict__ bsum, int nb)
{
    __shared__ int wtot[4], wexc[4];
    int tid = threadIdx.x;
    int lane = tid & 63, wid = tid >> 6;
    int v = (tid < nb) ? bsum[tid] : 0;
    int s = v;
    #pragma unroll
    for (int off = 1; off < 64; off <<= 1) {
        int u = __shfl_up(s, off);
        if (lane >= off) s += u;
    }
    if (lane == 63) wtot[wid] = s;
    __syncthreads();
    if (tid == 0) {
        int r = 0;
        #pragma unroll
        for (int w = 0; w < 4; ++w) { wexc[w] = r; r += wtot[w]; }
    }
    __syncthreads();
    if (tid < nb) bsum[tid] = s + wexc[wid] - v;
}

// ---------------------------------------------------------------------------
// Per-node GAT aggregation — node-per-half geometry + 8-edge batch with all
// loads hoisted (this round's single change): sv[8] -> av[8] -> hv[8] issue
// before any dependent math, giving ~8 h-gathers in flight per half-wave.
// ---------------------------------------------------------------------------
template<int LAYER>
__global__ __launch_bounds__(128) void gat_agg(
    const unsigned short* __restrict__ h, const float* __restrict__ a_s,
    const float* __restrict__ a_d, const int* __restrict__ rowptr,
    const int* __restrict__ esrc, const float* __restrict__ bias,
    float* __restrict__ out, unsigned short* __restrict__ out_b, int N)
{
    const int n  = blockIdx.x * 4 + (threadIdx.x >> 5);
    if (n >= N) return;
    const int sl   = threadIdx.x & 31;
    const int head = sl >> 2;
    const int beg = rowptr[n];
    const int deg = rowptr[n + 1] - beg;

    const float adn = a_d[(size_t)n*8 + head];
    float dsum = 0.f;
    float2 acc2[4] = {{0.f,0.f},{0.f,0.f},{0.f,0.f},{0.f,0.f}};

    int j0 = 0;
    for (; j0 + 8 <= deg; j0 += 8) {           // 8-edge batch, loads hoisted
        int sv[8];
        #pragma unroll
        for (int k = 0; k < 8; ++k) sv[k] = esrc[beg + j0 + k];
        float av[8];
        #pragma unroll
        for (int k = 0; k < 8; ++k) av[k] = a_s[(size_t)sv[k]*8 + head];
        uint4 hv[8];
        #pragma unroll
        for (int k = 0; k < 8; ++k)
            hv[k] = *(const uint4*)(h + (size_t)sv[k]*256 + sl*8);
        #pragma unroll
        for (int k = 0; k < 8; ++k) {
            float e = av[k] + adn;
            e = fmaxf(e, NEG_SLOPE * e);
            float p = __expf(e);
            dsum += p;
            const unsigned* hw = (const unsigned*)&hv[k];
            #pragma unroll
            for (int i = 0; i < 4; ++i) {
                acc2[i].x += p * __uint_as_float(hw[i] << 16);
                acc2[i].y += p * __uint_as_float(hw[i] & 0xffff0000u);
            }
        }
    }
    for (; j0 + 4 <= deg; j0 += 4) {
        int sv[4];
        #pragma unroll
        for (int k = 0; k < 4; ++k) sv[k] = esrc[beg + j0 + k];
        #pragma unroll
        for (int k = 0; k < 4; ++k) {
            int s = sv[k];
            float e = a_s[(size_t)s*8 + head] + adn;
            e = fmaxf(e, NEG_SLOPE * e);
            float p = __expf(e);
            dsum += p;
            uint4 hv = *(const uint4*)(h + (size_t)s*256 + sl*8);
            const unsigned* hw = (const unsigned*)&hv;
            #pragma unroll
            for (int i = 0; i < 4; ++i) {
                acc2[i].x += p * __uint_as_float(hw[i] << 16);
                acc2[i].y += p * __uint_as_float(hw[i] & 0xffff0000u);
            }
        }
    }
    for (; j0 < deg; ++j0) {
        int s = esrc[beg + j0];
        float e = a_s[(size_t)s*8 + head] + adn;
        e = fmaxf(e, NEG_SLOPE * e);
        float p = __expf(e);
        dsum += p;
        uint4 hv = *(const uint4*)(h + (size_t)s*256 + sl*8);
        const unsigned* hw = (const unsigned*)&hv;
        #pragma unroll
        for (int i = 0; i < 4; ++i) {
            acc2[i].x += p * __uint_as_float(hw[i] << 16);
            acc2[i].y += p * __uint_as_float(hw[i] & 0xffff0000u);
        }
    }

    float invd = 1.f / (dsum + 1e-16f);

    if (LAYER == 1) {
        ushortv8 o;
        #pragma unroll
        for (int i = 0; i < 4; ++i) {
            float v0 = acc2[i].x * invd + bias[sl*8 + 2*i];
            float v1 = acc2[i].y * invd + bias[sl*8 + 2*i + 1];
            o[2*i]   = f2bf(v0 > 0.f ? v0 : expf(v0) - 1.f);
            o[2*i+1] = f2bf(v1 > 0.f ? v1 : expf(v1) - 1.f);
        }
        *(ushortv8*)(out_b + (size_t)n*256 + sl*8) = o;
    } else {
        #pragma unroll
        for (int i = 0; i < 4; ++i) { acc2[i].x *= invd; acc2[i].y *= invd; }
        #pragma unroll
        for (int m = 4; m <= 16; m <<= 1)
            #pragma unroll
            for (int i = 0; i < 4; ++i) {
                acc2[i].x += __shfl_xor(acc2[i].x, m);
                acc2[i].y += __shfl_xor(acc2[i].y, m);
            }
        if (sl < 4) {
            float4 lo = make_float4(acc2[0].x*0.125f + bias[sl*8+0],
                                    acc2[0].y*0.125f + bias[sl*8+1],
                                    acc2[1].x*0.125f + bias[sl*8+2],
                                    acc2[1].y*0.125f + bias[sl*8+3]);
            float4 hi = make_float4(acc2[2].x*0.125f + bias[sl*8+4],
                                    acc2[2].y*0.125f + bias[sl*8+5],
                                    acc2[3].x*0.125f + bias[sl*8+6],
                                    acc2[3].y*0.125f + bias[sl*8+7]);
            *(float4*)(out + (size_t)n*32 + sl*8)     = lo;
            *(float4*)(out + (size_t)n*32 + sl*8 + 4) = hi;
        }
    }
}

// ---------------------------------------------------------------------------
extern "C" void kernel_launch(void* const* d_in, const int* in_sizes, int n_in,
                              void* d_out, int out_size, void* d_ws, size_t ws_size,
                              hipStream_t stream)
{
    const float* x   = (const float*)d_in[0];
    const int*   ei  = (const int*)  d_in[1];
    const float* W1  = (const float*)d_in[2];
    const float* as1 = (const float*)d_in[3];
    const float* ad1 = (const float*)d_in[4];
    const float* b1  = (const float*)d_in[5];
    const float* W2  = (const float*)d_in[6];
    const float* as2 = (const float*)d_in[7];
    const float* ad2 = (const float*)d_in[8];
    const float* b2  = (const float*)d_in[9];

    const int N = in_sizes[0] / 128;
    const int E = in_sizes[1] / 2;
    const int* srcp = ei;
    const int* dstp = ei + E;

    // ---- workspace layout ----
    char* ws = (char*)d_ws;
    unsigned short* hb    = (unsigned short*)ws;  ws += (size_t)N * 256 * 2;
    unsigned short* out1b = (unsigned short*)ws;  ws += (size_t)N * 256 * 2;
    unsigned short* Wt1   = (unsigned short*)ws;  ws += 256 * 128 * 2;
    unsigned short* Wt2   = (unsigned short*)ws;  ws += 256 * 256 * 2;
    float*          a_s   = (float*)ws;           ws += (size_t)N * 8 * 4;
    float*          a_d   = (float*)ws;           ws += (size_t)N * 8 * 4;
    int*            counts= (int*)ws;             ws += (size_t)N * 4;
    int*            cursor= (int*)ws;             ws += (size_t)N * 4;
    int*            incl  = (int*)ws;             ws += (size_t)N * 4;
    int*            bsum  = (int*)ws;             ws += 256 * 4;
    int*            rowptr= (int*)ws;             ws += (size_t)(N + 1) * 4;
    int*            esrc  = (int*)ws;

    const int nb = (N + 255) / 256;

    {
        int tot = 32768 + 65536 + N;
        prep_kernel<<<(tot + 255) / 256, 256, 0, stream>>>(
            W1, Wt1, W2, Wt2, counts, cursor, N);
    }
    hist_kernel<<<(E + 255) / 256, 256, 0, stream>>>(dstp, counts, E);
    scan_blk<<<nb, 256, 0, stream>>>(counts, incl, bsum, N);
    scan_top<<<1, 256, 0, stream>>>(bsum, nb);

    const int gridM = (N + 63) / 64;
    const int fillB = (E + 511) / 512;

    // ---- layer 1: gemm1 (+ piggy-backed CSR fill blocks) ----
    gemm_mfma<1><<<gridM + fillB, 512, 0, stream>>>(
        x, Wt1, hb, as1, ad1, a_s, a_d, N, 128, gridM,
        srcp, dstp, incl, bsum, rowptr, cursor, esrc, E);
    gat_agg<1><<<(N + 3) / 4, 128, 0, stream>>>(hb, a_s, a_d, rowptr, esrc, b1,
                                                nullptr, out1b, N);

    // ---- layer 2 ----
    gemm_mfma<0><<<gridM, 512, 0, stream>>>(
        out1b, Wt2, hb, as2, ad2, a_s, a_d, N, 256, gridM,
        srcp, dstp, incl, bsum, rowptr, cursor, esrc, E);
    gat_agg<2><<<(N + 3) / 4, 128, 0, stream>>>(hb, a_s, a_d, rowptr, esrc, b2,
                                                (float*)d_out, nullptr, N);
}

// Round 18
// 166.953 us; speedup vs baseline: 1.1921x; 1.0444x over previous
//
#include <hip/hip_runtime.h>
#include <math.h>

#define NEG_SLOPE 0.2f

typedef float f32x4 __attribute__((ext_vector_type(4)));
typedef short bf16x8 __attribute__((ext_vector_type(8)));
typedef unsigned short ushortv8 __attribute__((ext_vector_type(8)));

__device__ __forceinline__ unsigned short f2bf(float f) {
    union { float f; unsigned u; } uu; uu.f = f;
    unsigned r = uu.u + 0x7FFF + ((uu.u >> 16) & 1);   // RNE, no NaN inputs
    return (unsigned short)(r >> 16);
}
__device__ __forceinline__ float bf2f(unsigned short u) {
    union { unsigned u; float f; } x; x.u = ((unsigned)u) << 16; return x.f;
}

// ---------------------------------------------------------------------------
// prep: W1 transpose | W2 transpose | zero counts+cursor.
// ---------------------------------------------------------------------------
__global__ void prep_kernel(const float* __restrict__ W1, unsigned short* __restrict__ Wt1,
                            const float* __restrict__ W2, unsigned short* __restrict__ Wt2,
                            int* __restrict__ counts, int* __restrict__ cursor, int N)
{
    int u = blockIdx.x * 256 + threadIdx.x;
    if (u < 32768) {                       // Wt1[256][128]
        int nn = u >> 7, k = u & 127;
        Wt1[u] = f2bf(W1[(size_t)k * 256 + nn]);
        return;
    }
    u -= 32768;
    if (u < 65536) {                       // Wt2[256][256]
        int nn = u >> 8, k = u & 255;
        Wt2[u] = f2bf(W2[(size_t)k * 256 + nn]);
        return;
    }
    u -= 65536;
    if (u < N) { counts[u] = 0; cursor[u] = 0; }
}

__global__ void hist_kernel(const int* __restrict__ dst, int* __restrict__ counts, int E)
{
    int e = blockIdx.x * 256 + threadIdx.x;
    if (e < E) atomicAdd(&counts[dst[e]], 1);
}

// ---------------------------------------------------------------------------
// MFMA GEMM — this round: 256 thr, BM=64 x BN=128, 4 waves (2x2, each 32x64),
// LDS 24KB, 1D grid (col half = bid&1, row panel = bid>>1) -> 1564 blocks
// (~6/CU): more independent load->barrier->MFMA chains per CU. Pipelined
// staging, fused att epilogue, piggy-backed CSR fill after gemmBlocks.
// ---------------------------------------------------------------------------
template<int CVT>
__global__ __launch_bounds__(256) void gemm_mfma(
    const void* __restrict__ Av,
    const unsigned short* __restrict__ Bt,     // [256][K]
    unsigned short* __restrict__ C,            // [M][256]
    const float* __restrict__ att_s,           // flat [256]
    const float* __restrict__ att_d,
    float* __restrict__ a_s,                   // [M][8]
    float* __restrict__ a_d,
    int M, int K, int gemmBlocks,
    const int* __restrict__ srcp, const int* __restrict__ dstp,
    const int* __restrict__ incl, const int* __restrict__ bsum,
    int* __restrict__ rowptr, int* __restrict__ cursor,
    int* __restrict__ esrc, int E)
{
    __shared__ unsigned short As[64 * 64];     // 8KB
    __shared__ unsigned short Bs[128 * 64];    // 16KB

    if ((int)blockIdx.x >= gemmBlocks) {       // ---- CSR fill path ----
        int t = ((int)blockIdx.x - gemmBlocks) * 256 + threadIdx.x;
        if (t < M) {
            rowptr[t + 1] = incl[t] + bsum[t >> 8];
            if (t == 0) rowptr[0] = 0;
        }
        if (t < E) {
            int d = dstp[t];
            int rp = bsum[d >> 8] + ((d & 255) ? incl[d - 1] : 0);
            int pos = rp + atomicAdd(&cursor[d], 1);
            esrc[pos] = srcp[t];
        }
        return;
    }

    const int tid  = threadIdx.x;
    const int lane = tid & 63;
    const int wave = tid >> 6;
    const int wr = wave >> 1, wc = wave & 1;   // 2x2 wave grid, 32x64 each
    const int cb   = blockIdx.x & 1;           // col half (0: cols 0-127)
    const int row0 = (blockIdx.x >> 1) * 64;
    const int col0 = cb * 128;
    const int l15  = lane & 15;

    f32x4 acc[2][4] = {};
    ushortv8 va[2], vb[4];

    auto load_tile = [&](int k0) {
        #pragma unroll
        for (int i = 0; i < 2; ++i) {          // A: 512 chunks / 256 thr
            int c  = i * 256 + tid;
            int r  = c >> 3, cc = c & 7;
            int ga = row0 + r; if (ga >= M) ga = M - 1;
            if constexpr (CVT) {
                const float* ap = (const float*)Av + (size_t)ga * K + k0 + cc * 8;
                float4 lo = *(const float4*)ap;
                float4 hi = *(const float4*)(ap + 4);
                ushortv8 o;
                o[0]=f2bf(lo.x); o[1]=f2bf(lo.y); o[2]=f2bf(lo.z); o[3]=f2bf(lo.w);
                o[4]=f2bf(hi.x); o[5]=f2bf(hi.y); o[6]=f2bf(hi.z); o[7]=f2bf(hi.w);
                va[i] = o;
            } else {
                va[i] = *(const ushortv8*)((const unsigned short*)Av +
                                           (size_t)ga * K + k0 + cc * 8);
            }
        }
        #pragma unroll
        for (int i = 0; i < 4; ++i) {          // B: 1024 chunks / 256 thr
            int c  = i * 256 + tid;
            int r  = c >> 3, cc = c & 7;
            vb[i] = *(const ushortv8*)(Bt + (size_t)(col0 + r) * K + k0 + cc * 8);
        }
    };

    load_tile(0);                              // prologue

    for (int k0 = 0; k0 < K; k0 += 64) {
        __syncthreads();                       // prior MFMA done reading LDS
        #pragma unroll
        for (int i = 0; i < 2; ++i) {
            int c  = i * 256 + tid;
            int r  = c >> 3, cc = c & 7;
            *(ushortv8*)(As + r * 64 + (cc ^ (r & 7)) * 8) = va[i];
        }
        #pragma unroll
        for (int i = 0; i < 4; ++i) {
            int c  = i * 256 + tid;
            int r  = c >> 3, cc = c & 7;
            *(ushortv8*)(Bs + r * 64 + (cc ^ (r & 7)) * 8) = vb[i];
        }
        __syncthreads();

        if (k0 + 64 < K) load_tile(k0 + 64);   // latency hides under MFMAs

        #pragma unroll
        for (int kk = 0; kk < 2; ++kk) {
            const int kbyte = kk * 64 + ((lane >> 4) << 4);
            bf16x8 af[2], bfr[4];
            #pragma unroll
            for (int m = 0; m < 2; ++m) {
                int r = wr * 32 + m * 16 + l15;
                af[m] = *(const bf16x8*)((const char*)As + r * 128 + (kbyte ^ ((r & 7) << 4)));
            }
            #pragma unroll
            for (int n = 0; n < 4; ++n) {
                int r = wc * 64 + n * 16 + l15;
                bfr[n] = *(const bf16x8*)((const char*)Bs + r * 128 + (kbyte ^ ((r & 7) << 4)));
            }
            #pragma unroll
            for (int m = 0; m < 2; ++m)
                #pragma unroll
                for (int n = 0; n < 4; ++n)
                    acc[m][n] = __builtin_amdgcn_mfma_f32_16x16x32_bf16(
                        af[m], bfr[n], acc[m][n], 0, 0, 0);
        }
    }

    // ---- C store ----
    #pragma unroll
    for (int m = 0; m < 2; ++m) {
        int rbase = row0 + wr * 32 + m * 16 + ((lane >> 4) << 2);
        #pragma unroll
        for (int j = 0; j < 4; ++j) {
            int grow = rbase + j;
            if (grow < M) {
                #pragma unroll
                for (int n = 0; n < 4; ++n)
                    C[(size_t)grow * 256 + col0 + wc * 64 + n * 16 + l15] =
                        f2bf(acc[m][n][j]);
            }
        }
    }

    // ---- fused attention logits (wave covers heads cb*4+wc*2, +1) ----
    float asv[4], adv[4];
    #pragma unroll
    for (int n = 0; n < 4; ++n) {
        int colg = col0 + wc * 64 + n * 16 + l15;
        asv[n] = att_s[colg];
        adv[n] = att_d[colg];
    }
    const int hbase = cb * 4 + wc * 2;
    #pragma unroll
    for (int m = 0; m < 2; ++m) {
        int rbase = row0 + wr * 32 + m * 16 + ((lane >> 4) << 2);
        #pragma unroll
        for (int j = 0; j < 4; ++j) {
            int grow = rbase + j;
            #pragma unroll
            for (int t = 0; t < 2; ++t) {
                float vs = acc[m][2*t][j] * asv[2*t] + acc[m][2*t+1][j] * asv[2*t+1];
                float vd = acc[m][2*t][j] * adv[2*t] + acc[m][2*t+1][j] * adv[2*t+1];
                #pragma unroll
                for (int off = 1; off < 16; off <<= 1) {
                    vs += __shfl_xor(vs, off);
                    vd += __shfl_xor(vd, off);
                }
                if (l15 == 0 && grow < M) {
                    a_s[(size_t)grow * 8 + hbase + t] = vs;
                    a_d[(size_t)grow * 8 + hbase + t] = vd;
                }
            }
        }
    }
}

// ---------------------------------------------------------------------------
// CSR scan kernels (verbatim)
// ---------------------------------------------------------------------------
__global__ __launch_bounds__(256) void scan_blk(
    const int* __restrict__ counts, int* __restrict__ incl, int* __restrict__ bsum, int N)
{
    __shared__ int wtot[4], wexc[4];
    int t = blockIdx.x * 256 + threadIdx.x;
    int lane = threadIdx.x & 63, wid = threadIdx.x >> 6;
    int v = (t < N) ? counts[t] : 0;
    int s = v;
    #pragma unroll
    for (int off = 1; off < 64; off <<= 1) {
        int u = __shfl_up(s, off);
        if (lane >= off) s += u;
    }
    if (lane == 63) wtot[wid] = s;
    __syncthreads();
    if (threadIdx.x == 0) {
        int r = 0;
        #pragma unroll
        for (int w = 0; w < 4; ++w) { wexc[w] = r; r += wtot[w]; }
    }
    __syncthreads();
    int out = s + wexc[wid];
    if (t < N) incl[t] = out;
    if (threadIdx.x == 255) bsum[blockIdx.x] = out;
}

__global__ __launch_bounds__(256) void scan_top(int* __restrict__ bsum, int nb)
{
    __shared__ int wtot[4], wexc[4];
    int tid = threadIdx.x;
    int lane = tid & 63, wid = tid >> 6;
    int v = (tid < nb) ? bsum[tid] : 0;
    int s = v;
    #pragma unroll
    for (int off = 1; off < 64; off <<= 1) {
        int u = __shfl_up(s, off);
        if (lane >= off) s += u;
    }
    if (lane == 63) wtot[wid] = s;
    __syncthreads();
    if (tid == 0) {
        int r = 0;
        #pragma unroll
        for (int w = 0; w < 4; ++w) { wexc[w] = r; r += wtot[w]; }
    }
    __syncthreads();
    if (tid < nb) bsum[tid] = s + wexc[wid] - v;
}

// ---------------------------------------------------------------------------
// Per-node GAT aggregation — node-per-half geometry, 4-edge batch
// (r12-exact, the proven agg floor: VGPR 36, occupancy ~63%, 39 µs).
// ---------------------------------------------------------------------------
template<int LAYER>
__global__ __launch_bounds__(128) void gat_agg(
    const unsigned short* __restrict__ h, const float* __restrict__ a_s,
    const float* __restrict__ a_d, const int* __restrict__ rowptr,
    const int* __restrict__ esrc, const float* __restrict__ bias,
    float* __restrict__ out, unsigned short* __restrict__ out_b, int N)
{
    const int n  = blockIdx.x * 4 + (threadIdx.x >> 5);
    if (n >= N) return;
    const int sl   = threadIdx.x & 31;
    const int head = sl >> 2;
    const int beg = rowptr[n];
    const int deg = rowptr[n + 1] - beg;

    const float adn = a_d[(size_t)n*8 + head];
    float dsum = 0.f;
    float2 acc2[4] = {{0.f,0.f},{0.f,0.f},{0.f,0.f},{0.f,0.f}};

    int j0 = 0;
    for (; j0 + 4 <= deg; j0 += 4) {
        int s0 = esrc[beg + j0 + 0];
        int s1 = esrc[beg + j0 + 1];
        int s2 = esrc[beg + j0 + 2];
        int s3 = esrc[beg + j0 + 3];
        int sv[4] = {s0, s1, s2, s3};
        #pragma unroll
        for (int k = 0; k < 4; ++k) {
            int s = sv[k];
            float e = a_s[(size_t)s*8 + head] + adn;
            e = fmaxf(e, NEG_SLOPE * e);
            float p = __expf(e);
            dsum += p;
            uint4 hv = *(const uint4*)(h + (size_t)s*256 + sl*8);
            const unsigned* hw = (const unsigned*)&hv;
            #pragma unroll
            for (int i = 0; i < 4; ++i) {
                acc2[i].x += p * __uint_as_float(hw[i] << 16);
                acc2[i].y += p * __uint_as_float(hw[i] & 0xffff0000u);
            }
        }
    }
    for (; j0 < deg; ++j0) {
        int s = esrc[beg + j0];
        float e = a_s[(size_t)s*8 + head] + adn;
        e = fmaxf(e, NEG_SLOPE * e);
        float p = __expf(e);
        dsum += p;
        uint4 hv = *(const uint4*)(h + (size_t)s*256 + sl*8);
        const unsigned* hw = (const unsigned*)&hv;
        #pragma unroll
        for (int i = 0; i < 4; ++i) {
            acc2[i].x += p * __uint_as_float(hw[i] << 16);
            acc2[i].y += p * __uint_as_float(hw[i] & 0xffff0000u);
        }
    }

    float invd = 1.f / (dsum + 1e-16f);

    if (LAYER == 1) {
        ushortv8 o;
        #pragma unroll
        for (int i = 0; i < 4; ++i) {
            float v0 = acc2[i].x * invd + bias[sl*8 + 2*i];
            float v1 = acc2[i].y * invd + bias[sl*8 + 2*i + 1];
            o[2*i]   = f2bf(v0 > 0.f ? v0 : expf(v0) - 1.f);
            o[2*i+1] = f2bf(v1 > 0.f ? v1 : expf(v1) - 1.f);
        }
        *(ushortv8*)(out_b + (size_t)n*256 + sl*8) = o;
    } else {
        #pragma unroll
        for (int i = 0; i < 4; ++i) { acc2[i].x *= invd; acc2[i].y *= invd; }
        #pragma unroll
        for (int m = 4; m <= 16; m <<= 1)
            #pragma unroll
            for (int i = 0; i < 4; ++i) {
                acc2[i].x += __shfl_xor(acc2[i].x, m);
                acc2[i].y += __shfl_xor(acc2[i].y, m);
            }
        if (sl < 4) {
            float4 lo = make_float4(acc2[0].x*0.125f + bias[sl*8+0],
                                    acc2[0].y*0.125f + bias[sl*8+1],
                                    acc2[1].x*0.125f + bias[sl*8+2],
                                    acc2[1].y*0.125f + bias[sl*8+3]);
            float4 hi = make_float4(acc2[2].x*0.125f + bias[sl*8+4],
                                    acc2[2].y*0.125f + bias[sl*8+5],
                                    acc2[3].x*0.125f + bias[sl*8+6],
                                    acc2[3].y*0.125f + bias[sl*8+7]);
            *(float4*)(out + (size_t)n*32 + sl*8)     = lo;
            *(float4*)(out + (size_t)n*32 + sl*8 + 4) = hi;
        }
    }
}

// ---------------------------------------------------------------------------
extern "C" void kernel_launch(void* const* d_in, const int* in_sizes, int n_in,
                              void* d_out, int out_size, void* d_ws, size_t ws_size,
                              hipStream_t stream)
{
    const float* x   = (const float*)d_in[0];
    const int*   ei  = (const int*)  d_in[1];
    const float* W1  = (const float*)d_in[2];
    const float* as1 = (const float*)d_in[3];
    const float* ad1 = (const float*)d_in[4];
    const float* b1  = (const float*)d_in[5];
    const float* W2  = (const float*)d_in[6];
    const float* as2 = (const float*)d_in[7];
    const float* ad2 = (const float*)d_in[8];
    const float* b2  = (const float*)d_in[9];

    const int N = in_sizes[0] / 128;
    const int E = in_sizes[1] / 2;
    const int* srcp = ei;
    const int* dstp = ei + E;

    // ---- workspace layout ----
    char* ws = (char*)d_ws;
    unsigned short* hb    = (unsigned short*)ws;  ws += (size_t)N * 256 * 2;
    unsigned short* out1b = (unsigned short*)ws;  ws += (size_t)N * 256 * 2;
    unsigned short* Wt1   = (unsigned short*)ws;  ws += 256 * 128 * 2;
    unsigned short* Wt2   = (unsigned short*)ws;  ws += 256 * 256 * 2;
    float*          a_s   = (float*)ws;           ws += (size_t)N * 8 * 4;
    float*          a_d   = (float*)ws;           ws += (size_t)N * 8 * 4;
    int*            counts= (int*)ws;             ws += (size_t)N * 4;
    int*            cursor= (int*)ws;             ws += (size_t)N * 4;
    int*            incl  = (int*)ws;             ws += (size_t)N * 4;
    int*            bsum  = (int*)ws;             ws += 256 * 4;
    int*            rowptr= (int*)ws;             ws += (size_t)(N + 1) * 4;
    int*            esrc  = (int*)ws;

    const int nb = (N + 255) / 256;

    {
        int tot = 32768 + 65536 + N;
        prep_kernel<<<(tot + 255) / 256, 256, 0, stream>>>(
            W1, Wt1, W2, Wt2, counts, cursor, N);
    }
    hist_kernel<<<(E + 255) / 256, 256, 0, stream>>>(dstp, counts, E);
    scan_blk<<<nb, 256, 0, stream>>>(counts, incl, bsum, N);
    scan_top<<<1, 256, 0, stream>>>(bsum, nb);

    const int gridM = (N + 63) / 64;
    const int gemmB = gridM * 2;               // col-half x row-panel
    const int fillB = (E + 255) / 256;

    // ---- layer 1: gemm1 (+ piggy-backed CSR fill blocks) ----
    gemm_mfma<1><<<gemmB + fillB, 256, 0, stream>>>(
        x, Wt1, hb, as1, ad1, a_s, a_d, N, 128, gemmB,
        srcp, dstp, incl, bsum, rowptr, cursor, esrc, E);
    gat_agg<1><<<(N + 3) / 4, 128, 0, stream>>>(hb, a_s, a_d, rowptr, esrc, b1,
                                                nullptr, out1b, N);

    // ---- layer 2 ----
    gemm_mfma<0><<<gemmB, 256, 0, stream>>>(
        out1b, Wt2, hb, as2, ad2, a_s, a_d, N, 256, gemmB,
        srcp, dstp, incl, bsum, rowptr, cursor, esrc, E);
    gat_agg<2><<<(N + 3) / 4, 128, 0, stream>>>(hb, a_s, a_d, rowptr, esrc, b2,
                                                (float*)d_out, nullptr, N);
}